// Round 10
// baseline (277.341 us; speedup 1.0000x reference)
//
#include <hip/hip_runtime.h>

// FreqLinear: out = Y2 @ float(idx)^T + corr[m] + bias[o], K = 2048.
// GEMM v10: BARRIER-FREE + LDS-FREE + VOLATILE-PINNED REGISTER PIPELINE.
// Root cause of R2..R9 (counter-verified): VGPR_Count 52-88 every round --
// the scheduler sinks/remats plain loads to uses, collapsing every software
// pipeline; and the "memory"-clobber barrier asm forced vmcnt drains.
// Fix: volatile ext-vector loads (cannot remat/duplicate/reorder) pin the
// ring in registers; no LDS, no barriers, no fences -> the only waits are
// compiler-exact minimal vmcnt(N) at first use.
// grid 256 x 512thr: block = 32 cols x 256 rows. wave w -> mg {2w, 2w+1}.
// Per kstep (K=32): 4 volatile B-loads (idx, HBM stream, ring depth 8 =
// ~8 ksteps lookahead), 2 volatile A-loads (Y2f frag-order, L2-hot, depth
// 4), cvt int->bf16 in-register (exact, <=255), 4 MFMAs. Each idx col read
// by exactly ONE block -> HBM idx traffic = 64 MB, no dedupe assumptions.

typedef int v4i __attribute__((ext_vector_type(4)));
typedef __attribute__((ext_vector_type(8))) short bf16x8;   // 8 bf16
typedef __attribute__((ext_vector_type(4))) float f32x4;

#define K_TOT   2048
#define N_TOT   8192

__device__ __forceinline__ unsigned short f2bf_rn(float f) {
    unsigned u = __float_as_uint(f);
    u += 0x7FFFu + ((u >> 16) & 1u);
    return (unsigned short)(u >> 16);
}
// two ints (0..255) -> exact floats -> packed bf16 pair (truncation exact)
__device__ __forceinline__ unsigned pk2(int a, int b) {
    unsigned ua = __float_as_uint((float)a);
    unsigned ub = __float_as_uint((float)b);
    return __builtin_amdgcn_perm(ub, ua, 0x07060302u);  // {ub.hi16, ua.hi16}
}
__device__ __forceinline__ bf16x8 cvt8(v4i lo, v4i hi) {
    union { unsigned u[4]; bf16x8 v; } r;
    r.u[0] = pk2(lo[0], lo[1]);
    r.u[1] = pk2(lo[2], lo[3]);
    r.u[2] = pk2(hi[0], hi[1]);
    r.u[3] = pk2(hi[2], hi[3]);
    return r.v;
}
__device__ __forceinline__ bf16x8 as_bf(v4i v) {
    union { v4i i; bf16x8 b; } u; u.i = v; return u.b;
}

// ---------------- Kernel A: build Y2f (bf16, frag order) + corr ------------
__global__ __launch_bounds__(256) void prep_kernel(
    const float* __restrict__ x, const float* __restrict__ c_min,
    const float* __restrict__ c_range, unsigned short* __restrict__ Y2f,
    float* __restrict__ corr)
{
    __shared__ float Bk[8][16];
    __shared__ float scmin[8];
    __shared__ float ss[8];
    __shared__ float red[4];
    const int tid = threadIdx.x;
    const int m = blockIdx.x;
    if (tid < 128) {
        int k = tid >> 4, t = tid & 15;
        float v = cosf(3.14159265358979f * (t + 0.5f) * (float)k / 16.0f)
                  * 0.353553390593274f;                 // sqrt(2/16)
        if (k == 0) v *= 0.707106781186548f;            // 1/sqrt(2)
        Bk[k][t] = v;
    }
    if (tid < 8) {
        scmin[tid] = c_min[tid];
        ss[tid] = c_range[tid] * (1.0f / 255.0f);
    }
    __syncthreads();

    const float* xp = x + (long)m * 4096 + tid * 16;
    float xs[16];
#pragma unroll
    for (int q = 0; q < 4; ++q) {
        float4 v = *(const float4*)(xp + q * 4);
        xs[q * 4 + 0] = v.x; xs[q * 4 + 1] = v.y;
        xs[q * 4 + 2] = v.z; xs[q * 4 + 3] = v.w;
    }
    float partial = 0.0f;
    unsigned short yo[8];
#pragma unroll
    for (int k = 0; k < 8; ++k) {
        float y = 0.0f;
#pragma unroll
        for (int t = 0; t < 16; ++t) y += xs[t] * Bk[k][t];
        partial += y * scmin[k];
        yo[k] = f2bf_rn(y * ss[k]);
    }
    uint4 pkv;
    pkv.x = (unsigned)yo[0] | ((unsigned)yo[1] << 16);
    pkv.y = (unsigned)yo[2] | ((unsigned)yo[3] << 16);
    pkv.z = (unsigned)yo[4] | ((unsigned)yo[5] << 16);
    pkv.w = (unsigned)yo[6] | ((unsigned)yo[7] << 16);
    // frag-order store: kc = tid>>2, fq = tid&3, mg = m>>4, fr = m&15
    {
        const int mg = m >> 4, fr = m & 15, kc = tid >> 2, fq = tid & 3;
        unsigned short* dst = Y2f + ((long)((mg * 64 + kc) * 64) + fq * 16 + fr) * 8;
        *(uint4*)dst = pkv;
    }
#pragma unroll
    for (int off = 32; off > 0; off >>= 1)
        partial += __shfl_down(partial, off, 64);
    if ((tid & 63) == 0) red[tid >> 6] = partial;
    __syncthreads();
    if (tid == 0) corr[m] = red[0] + red[1] + red[2] + red[3];
}

// ---------------- Kernel B ------------------------------------------------
#define VL(p, o) (*((const volatile v4i*)(p) + (o)))

__global__ __launch_bounds__(512, 2) void gemm_kernel(
    const unsigned short* __restrict__ Y2f, const int* __restrict__ idx,
    const float* __restrict__ bias, const float* __restrict__ corr,
    float* __restrict__ out)
{
    const int tid  = threadIdx.x;
    const int wave = tid >> 6;
    const int lane = tid & 63;
    const int fr   = lane & 15;
    const int fq   = lane >> 4;
    const int o0   = blockIdx.x * 32;

    // B streams: col g -> o0 + g*16 + fr; per kstep 128 B/col (8 v4i)
    const v4i* b0 = (const v4i*)(idx + (long)(o0 + fr) * K_TOT + fq * 8);
    const v4i* b1 = (const v4i*)(idx + (long)(o0 + 16 + fr) * K_TOT + fq * 8);
    // A frags (frag-order Y2f): mg = wave*2+mt; byte addr mg*65536+ks*1024+lane*16
    const v4i* a0 = (const v4i*)((const char*)Y2f + (long)(wave * 2 + 0) * 65536 + lane * 16);
    const v4i* a1 = (const v4i*)((const char*)Y2f + (long)(wave * 2 + 1) * 65536 + lane * 16);

    v4i B[8][4];   // B ring: 8 ksteps x {g0lo, g0hi, g1lo, g1hi}
    v4i A[4][2];   // A ring: 4 ksteps x {mt0, mt1}

    // prologue: fill rings (all volatile -> pinned issue order & residency)
#pragma unroll
    for (int s = 0; s < 8; ++s) {
        B[s][0] = VL(b0, s * 8);     B[s][1] = VL(b0, s * 8 + 1);
        B[s][2] = VL(b1, s * 8);     B[s][3] = VL(b1, s * 8 + 1);
    }
#pragma unroll
    for (int d = 0; d < 4; ++d) {
        A[d][0] = VL(a0, d * 64);    A[d][1] = VL(a1, d * 64);
    }

    f32x4 acc[2][2];
#pragma unroll
    for (int mt = 0; mt < 2; ++mt)
#pragma unroll
        for (int g = 0; g < 2; ++g)
            acc[mt][g] = (f32x4){0.f, 0.f, 0.f, 0.f};

    const v4i* b0c = b0; const v4i* b1c = b1;
    const v4i* a0c = a0; const v4i* a1c = a1;

    // main: kk = 0..6 (ks = kk*8 + s, s = 0..7); all reissue targets <= 63
    for (int kk = 0; kk < 7; ++kk) {
#pragma unroll
        for (int s = 0; s < 8; ++s) {
            bf16x8 bf0 = cvt8(B[s][0], B[s][1]);
            bf16x8 bf1 = cvt8(B[s][2], B[s][3]);
            bf16x8 af0 = as_bf(A[s & 3][0]);
            bf16x8 af1 = as_bf(A[s & 3][1]);
            acc[0][0] = __builtin_amdgcn_mfma_f32_16x16x32_bf16(af0, bf0, acc[0][0], 0, 0, 0);
            acc[1][0] = __builtin_amdgcn_mfma_f32_16x16x32_bf16(af1, bf0, acc[1][0], 0, 0, 0);
            acc[0][1] = __builtin_amdgcn_mfma_f32_16x16x32_bf16(af0, bf1, acc[0][1], 0, 0, 0);
            acc[1][1] = __builtin_amdgcn_mfma_f32_16x16x32_bf16(af1, bf1, acc[1][1], 0, 0, 0);
            // reissue: B slot s <- ks+8 ; A slot s&3 <- ks+4
            B[s][0] = VL(b0c, (s + 8) * 8);     B[s][1] = VL(b0c, (s + 8) * 8 + 1);
            B[s][2] = VL(b1c, (s + 8) * 8);     B[s][3] = VL(b1c, (s + 8) * 8 + 1);
            A[s & 3][0] = VL(a0c, (s + 4) * 64);
            A[s & 3][1] = VL(a1c, (s + 4) * 64);
        }
        b0c += 64; b1c += 64;       // 8 ksteps * 128 B
        a0c += 512; a1c += 512;     // 8 ksteps * 1 KB
    }
    // tail: ks = 56..63 (B ring full; A reissue only while target < 64)
#pragma unroll
    for (int s = 0; s < 8; ++s) {
        bf16x8 bf0 = cvt8(B[s][0], B[s][1]);
        bf16x8 bf1 = cvt8(B[s][2], B[s][3]);
        bf16x8 af0 = as_bf(A[s & 3][0]);
        bf16x8 af1 = as_bf(A[s & 3][1]);
        acc[0][0] = __builtin_amdgcn_mfma_f32_16x16x32_bf16(af0, bf0, acc[0][0], 0, 0, 0);
        acc[1][0] = __builtin_amdgcn_mfma_f32_16x16x32_bf16(af1, bf0, acc[1][0], 0, 0, 0);
        acc[0][1] = __builtin_amdgcn_mfma_f32_16x16x32_bf16(af0, bf1, acc[0][1], 0, 0, 0);
        acc[1][1] = __builtin_amdgcn_mfma_f32_16x16x32_bf16(af1, bf1, acc[1][1], 0, 0, 0);
        if (s < 4) {                // targets 60..63, used at s = 4..7
            A[s & 3][0] = VL(a0c, (s + 4) * 64);
            A[s & 3][1] = VL(a1c, (s + 4) * 64);
        }
    }

    // epilogue: D layout col = lane&15, row = (lane>>4)*4 + reg
#pragma unroll
    for (int mt = 0; mt < 2; ++mt) {
        const int row0 = (wave * 2 + mt) * 16 + fq * 4;
#pragma unroll
        for (int g = 0; g < 2; ++g) {
            const int col = o0 + g * 16 + fr;
            const float bv = bias[col];
#pragma unroll
            for (int r = 0; r < 4; ++r)
                out[(long)(row0 + r) * N_TOT + col] =
                    acc[mt][g][r] + bv + corr[row0 + r];
        }
    }
}

extern "C" void kernel_launch(void* const* d_in, const int* in_sizes, int n_in,
                              void* d_out, int out_size, void* d_ws, size_t ws_size,
                              hipStream_t stream) {
    const float* x       = (const float*)d_in[0];   // [32,8,4096]
    const int*   idx     = (const int*)d_in[1];     // [2097152, 8]
    const float* c_min   = (const float*)d_in[2];   // [8]
    const float* c_range = (const float*)d_in[3];   // [8]
    const float* bias    = (const float*)d_in[4];   // [8192]
    float* out = (float*)d_out;                     // [256, 8192]

    unsigned short* Y2f = (unsigned short*)d_ws;                   // 1 MB
    float* corr = (float*)((char*)d_ws + (size_t)256 * K_TOT * 2); // 256 fp32

    prep_kernel<<<256, 256, 0, stream>>>(x, c_min, c_range, Y2f, corr);
    gemm_kernel<<<N_TOT / 32, 512, 0, stream>>>(Y2f, idx, bias, corr, out);
}